// Round 11
// baseline (770.832 us; speedup 1.0000x reference)
//
#include <hip/hip_runtime.h>
#include <hip/hip_bf16.h>

typedef __attribute__((ext_vector_type(8))) short short8;
typedef __attribute__((ext_vector_type(4))) float f32x4;

#define SEQ 8192
#define NBATCH 4
#define NT (SEQ / 32)

static __device__ __forceinline__ unsigned short f2bf(float f) {
    __hip_bfloat16 h = __float2bfloat16(f);
    unsigned short u;
    __builtin_memcpy(&u, &h, 2);
    return u;
}

static __device__ __forceinline__ int4 pack8(float4 a, float4 b) {
    union { unsigned short s[8]; int4 i; } r;
    r.s[0] = f2bf(a.x); r.s[1] = f2bf(a.y); r.s[2] = f2bf(a.z); r.s[3] = f2bf(a.w);
    r.s[4] = f2bf(b.x); r.s[5] = f2bf(b.y); r.s[6] = f2bf(b.z); r.s[7] = f2bf(b.w);
    return r.i;
}

// C[M][N] = A[M][256] * W[N][256]^T (+bias)*scale.  Tile 128x128, 4 waves.
// OMODE: 0 = bf16 row-major, 1 = f32 row-major, 2 = bf16 transposed per batch
// (out[(b*256+col)*8192 + s], for V^T). (verified rounds 2-6)
template<bool A_BF16, int OMODE>
__global__ __launch_bounds__(256) void proj_gemm(
    const void* __restrict__ Ap, const float* __restrict__ W,
    const float* __restrict__ bias, void* __restrict__ Outp, float scale)
{
    __shared__ alignas(16) unsigned short As[128][40];
    __shared__ alignas(16) unsigned short Bs[128][40];

    const int tid  = threadIdx.x;
    const int lane = tid & 63;
    const int wv   = tid >> 6;
    const int wm   = (wv >> 1) * 64, wn = (wv & 1) * 64;
    const int lr   = lane & 15, lg = lane >> 4;
    const int m0   = blockIdx.x * 128;
    const int n0   = blockIdx.y * 128;

    const int srow = tid >> 1;
    const int skc  = (tid & 1) * 16;

    f32x4 acc[4][4] = {};

    for (int k0 = 0; k0 < 256; k0 += 32) {
        __syncthreads();
        if (A_BF16) {
            const unsigned short* a = (const unsigned short*)Ap + (size_t)(m0 + srow) * 256 + k0 + skc;
            int4 v0 = *(const int4*)a;
            int4 v1 = *(const int4*)(a + 8);
            *(int4*)&As[srow][skc]     = v0;
            *(int4*)&As[srow][skc + 8] = v1;
        } else {
            const float* a = (const float*)Ap + (size_t)(m0 + srow) * 256 + k0 + skc;
            const float4* a4 = (const float4*)a;
            *(int4*)&As[srow][skc]     = pack8(a4[0], a4[1]);
            *(int4*)&As[srow][skc + 8] = pack8(a4[2], a4[3]);
        }
        {
            const float* b = W + (size_t)(n0 + srow) * 256 + k0 + skc;
            const float4* b4 = (const float4*)b;
            *(int4*)&Bs[srow][skc]     = pack8(b4[0], b4[1]);
            *(int4*)&Bs[srow][skc + 8] = pack8(b4[2], b4[3]);
        }
        __syncthreads();

        short8 af[4], bfr[4];
        #pragma unroll
        for (int fm = 0; fm < 4; ++fm)
            af[fm] = *(const short8*)&As[wm + fm * 16 + lr][lg * 8];
        #pragma unroll
        for (int fn = 0; fn < 4; ++fn)
            bfr[fn] = *(const short8*)&Bs[wn + fn * 16 + lr][lg * 8];
        #pragma unroll
        for (int fm = 0; fm < 4; ++fm)
            #pragma unroll
            for (int fn = 0; fn < 4; ++fn)
                acc[fm][fn] = __builtin_amdgcn_mfma_f32_16x16x32_bf16(
                    af[fm], bfr[fn], acc[fm][fn], 0, 0, 0);
    }

    float bvals[4];
    #pragma unroll
    for (int fn = 0; fn < 4; ++fn) bvals[fn] = bias[n0 + wn + fn * 16 + lr];

    #pragma unroll
    for (int fm = 0; fm < 4; ++fm) {
        #pragma unroll
        for (int fn = 0; fn < 4; ++fn) {
            #pragma unroll
            for (int r = 0; r < 4; ++r) {
                const int row = m0 + wm + fm * 16 + lg * 4 + r;
                const int col = n0 + wn + fn * 16 + lr;
                float val = (acc[fm][fn][r] + bvals[fn]) * scale;
                if (OMODE == 1) {
                    ((float*)Outp)[(size_t)row * 256 + col] = val;
                } else if (OMODE == 0) {
                    ((unsigned short*)Outp)[(size_t)row * 256 + col] = f2bf(val);
                } else {  // V^T: [b][d=col][s]
                    const int bb = row >> 13, s = row & 8191;
                    ((unsigned short*)Outp)[((size_t)(bb * 256 + col) << 13) + s] = f2bf(val);
                }
            }
        }
    }
}

// Flash attention, round 11 = round 10 (best verified: 459us) + two changes:
// 1. P-pack via v_cvt_pk_bf16_f32 inline asm (4 insts replace 8 RNE casts
//    + 6 pack ops) — VALU is the bottleneck at 53.5% busy.
// 2. s_setprio(1) around QK and PV MFMA clusters (T5, attn-proven).
// Verified r10 components: conflict-free 128B-interleaved K staging, swapped
// QK (D[kv][q]), per-lane log2 softmax, defer-rescale THR=11, Ps/Cor/Flg
// dbuf, PV lags 1 iter, V^T direct from global, one barrier/iter.
__global__ __launch_bounds__(256) void attn_kernel(
    const unsigned short* __restrict__ Q, const unsigned short* __restrict__ K,
    const unsigned short* __restrict__ Vt, unsigned short* __restrict__ A)
{
    __shared__ alignas(16) unsigned short Ks[2][32][264];   // [buf][kv][d], pad +8
    __shared__ alignas(16) unsigned short Ps[2][4][16][40]; // [buf][qt][q][kv]
    __shared__ alignas(16) float Cor[2][4][16];
    __shared__ alignas(16) float Ls[4][16];
    __shared__ int Flg[2][4];

    const int tid  = threadIdx.x;
    const int lane = tid & 63;
    const int wv   = tid >> 6;
    const int lr   = lane & 15, lg = lane >> 4;
    const int b    = blockIdx.y;
    const size_t qblk = (size_t)b * SEQ + blockIdx.x * 64;

    // Q frags (B-operand): wave wv owns q-tile wv
    short8 aq[8];
    #pragma unroll
    for (int c = 0; c < 8; ++c)
        aq[c] = *(const short8*)&Q[(qblk + wv * 16 + lr) * 256 + c * 32 + lg * 8];

    float m_run = -1e30f, l_run = 0.f;   // per-lane: q-row = lr (log2 domain)
    f32x4 o[4][4] = {};   // [qt][dt]: rows qt*16+lg*4+r, cols wv*64+dt*16+lr

    const int krow = tid >> 3;           // K staging: row 0..31
    const int kc8  = (tid & 7) * 8;      // chunk element offset (16B chunks)
    const unsigned short* Kb = K + (size_t)b * SEQ * 256;
    const unsigned short* Vb = Vt + ((size_t)b * 256 << 13);
    size_t vrow[4];
    #pragma unroll
    for (int dt = 0; dt < 4; ++dt)
        vrow[dt] = (size_t)(wv * 64 + dt * 16 + lr) << 13;

    // prologue: stage tile 0 into Ks[0] (128B-interleaved chunks)
    {
        const unsigned short* s = &Kb[(size_t)krow * 256 + kc8];
        int4 x0 = *(const int4*)(s);
        int4 x1 = *(const int4*)(s + 64);
        int4 x2 = *(const int4*)(s + 128);
        int4 x3 = *(const int4*)(s + 192);
        *(int4*)&Ks[0][krow][kc8]       = x0;
        *(int4*)&Ks[0][krow][kc8 + 64]  = x1;
        *(int4*)&Ks[0][krow][kc8 + 128] = x2;
        *(int4*)&Ks[0][krow][kc8 + 192] = x3;
    }
    __syncthreads();

    for (int t = 0; t < NT; ++t) {
        const int p = t & 1;
        const bool have = (t + 1 < NT);

        // issue K(t+1) loads early (latency hides under QK)
        int4 x0, x1, x2, x3;
        if (have) {
            const unsigned short* s = &Kb[((size_t)(t + 1) * 32 + krow) * 256 + kc8];
            x0 = *(const int4*)(s);
            x1 = *(const int4*)(s + 64);
            x2 = *(const int4*)(s + 128);
            x3 = *(const int4*)(s + 192);
        }
        // V^T frags for PV(t-1), direct from global (L2-resident)
        short8 vbr[4];
        if (t > 0) {
            const size_t kvp = (size_t)(t - 1) * 32 + lg * 8;
            #pragma unroll
            for (int dt = 0; dt < 4; ++dt)
                vbr[dt] = *(const short8*)&Vb[vrow[dt] + kvp];
        }

        // QK(t) from Ks[p] (swapped): s0 = kv 0..15, s1 = kv 16..31
        f32x4 s0 = {}, s1 = {};
        __builtin_amdgcn_s_setprio(1);
        #pragma unroll
        for (int c = 0; c < 8; ++c) {
            short8 kb0 = *(const short8*)&Ks[p][lr][c * 32 + lg * 8];
            short8 kb1 = *(const short8*)&Ks[p][16 + lr][c * 32 + lg * 8];
            s0 = __builtin_amdgcn_mfma_f32_16x16x32_bf16(kb0, aq[c], s0, 0, 0, 0);
            s1 = __builtin_amdgcn_mfma_f32_16x16x32_bf16(kb1, aq[c], s1, 0, 0, 0);
        }
        __builtin_amdgcn_s_setprio(0);

        // write staged K(t+1) into the other buffer (conflict-free map)
        if (have) {
            *(int4*)&Ks[p ^ 1][krow][kc8]       = x0;
            *(int4*)&Ks[p ^ 1][krow][kc8 + 64]  = x1;
            *(int4*)&Ks[p ^ 1][krow][kc8 + 128] = x2;
            *(int4*)&Ks[p ^ 1][krow][kc8 + 192] = x3;
        }

        // online softmax for q=lr (log2 domain), defer-rescale THR=11
        float mx = fmaxf(fmaxf(fmaxf(s0[0], s0[1]), fmaxf(s0[2], s0[3])),
                         fmaxf(fmaxf(s1[0], s1[1]), fmaxf(s1[2], s1[3])));
        mx = fmaxf(mx, __shfl_xor(mx, 16, 64));
        mx = fmaxf(mx, __shfl_xor(mx, 32, 64));

        const int need = __any(mx > m_run + 11.0f);
        float corr = 1.f;
        if (need) {
            float mnew = fmaxf(m_run, mx);
            corr = exp2f(m_run - mnew);
            m_run = mnew;
            if (lane < 16) Cor[p ^ 1][wv][lr] = corr;
        }
        if (lane == 0) Flg[p ^ 1][wv] = need;

        float p0[4], p1[4];
        #pragma unroll
        for (int r = 0; r < 4; ++r) {
            p0[r] = exp2f(s0[r] - m_run);
            p1[r] = exp2f(s1[r] - m_run);
        }
        float rs = ((p0[0] + p0[1]) + (p0[2] + p0[3])) +
                   ((p1[0] + p1[1]) + (p1[2] + p1[3]));
        rs += __shfl_xor(rs, 16, 64);
        rs += __shfl_xor(rs, 32, 64);
        l_run = (need ? l_run * corr : l_run) + rs;

        {   // pack P -> Ps[p^1] via v_cvt_pk_bf16_f32 (RNE), 2x b64 writes
            unsigned int w0, w1, w2, w3;
            asm("v_cvt_pk_bf16_f32 %0, %1, %2" : "=v"(w0) : "v"(p0[0]), "v"(p0[1]));
            asm("v_cvt_pk_bf16_f32 %0, %1, %2" : "=v"(w1) : "v"(p0[2]), "v"(p0[3]));
            asm("v_cvt_pk_bf16_f32 %0, %1, %2" : "=v"(w2) : "v"(p1[0]), "v"(p1[1]));
            asm("v_cvt_pk_bf16_f32 %0, %1, %2" : "=v"(w3) : "v"(p1[2]), "v"(p1[3]));
            *(unsigned long long*)&Ps[p ^ 1][wv][lr][4 * lg] =
                (unsigned long long)w0 | ((unsigned long long)w1 << 32);
            *(unsigned long long*)&Ps[p ^ 1][wv][lr][16 + 4 * lg] =
                (unsigned long long)w2 | ((unsigned long long)w3 << 32);
        }

        // PV(t-1): P from Ps[p], rescale via Flg/Cor[p], V frags from global
        if (t > 0) {
            short8 pa[4];
            #pragma unroll
            for (int qt = 0; qt < 4; ++qt)
                pa[qt] = *(const short8*)&Ps[p][qt][lr][lg * 8];
            #pragma unroll
            for (int qt = 0; qt < 4; ++qt) {
                if (Flg[p][qt]) {
                    float4 c4 = *(const float4*)&Cor[p][qt][lg * 4];
                    #pragma unroll
                    for (int dt = 0; dt < 4; ++dt) {
                        o[qt][dt][0] *= c4.x; o[qt][dt][1] *= c4.y;
                        o[qt][dt][2] *= c4.z; o[qt][dt][3] *= c4.w;
                    }
                }
            }
            __builtin_amdgcn_s_setprio(1);
            #pragma unroll
            for (int qt = 0; qt < 4; ++qt)
                #pragma unroll
                for (int dt = 0; dt < 4; ++dt)
                    o[qt][dt] = __builtin_amdgcn_mfma_f32_16x16x32_bf16(pa[qt], vbr[dt], o[qt][dt], 0, 0, 0);
            __builtin_amdgcn_s_setprio(0);
        }
        __syncthreads();   // Ks[p^1] + Ps/Cor/Flg[p^1] visible; reads of [p] done
    }

    // epilogue: PV(NT-1) from Ps[NT&1]
    {
        const int p = NT & 1;
        const size_t kvp = (size_t)(NT - 1) * 32 + lg * 8;
        short8 vbr[4];
        #pragma unroll
        for (int dt = 0; dt < 4; ++dt)
            vbr[dt] = *(const short8*)&Vb[vrow[dt] + kvp];
        short8 pa[4];
        #pragma unroll
        for (int qt = 0; qt < 4; ++qt)
            pa[qt] = *(const short8*)&Ps[p][qt][lr][lg * 8];
        #pragma unroll
        for (int qt = 0; qt < 4; ++qt) {
            if (Flg[p][qt]) {
                float4 c4 = *(const float4*)&Cor[p][qt][lg * 4];
                #pragma unroll
                for (int dt = 0; dt < 4; ++dt) {
                    o[qt][dt][0] *= c4.x; o[qt][dt][1] *= c4.y;
                    o[qt][dt][2] *= c4.z; o[qt][dt][3] *= c4.w;
                }
            }
            #pragma unroll
            for (int dt = 0; dt < 4; ++dt)
                o[qt][dt] = __builtin_amdgcn_mfma_f32_16x16x32_bf16(pa[qt], vbr[dt], o[qt][dt], 0, 0, 0);
        }
    }

    // broadcast l, normalize, write
    if (lane < 16) Ls[wv][lr] = l_run;
    __syncthreads();
    #pragma unroll
    for (int qt = 0; qt < 4; ++qt) {
        float4 l4 = *(const float4*)&Ls[qt][lg * 4];
        float inv[4] = {1.f / l4.x, 1.f / l4.y, 1.f / l4.z, 1.f / l4.w};
        #pragma unroll
        for (int dt = 0; dt < 4; ++dt)
            #pragma unroll
            for (int r = 0; r < 4; ++r)
                A[(qblk + qt * 16 + lg * 4 + r) * 256 + wv * 64 + dt * 16 + lr] =
                    f2bf(o[qt][dt][r] * inv[r]);
    }
}

extern "C" void kernel_launch(void* const* d_in, const int* in_sizes, int n_in,
                              void* d_out, int out_size, void* d_ws, size_t ws_size,
                              hipStream_t stream) {
    (void)in_sizes; (void)n_in; (void)out_size; (void)ws_size;
    const float* x  = (const float*)d_in[0];
    const float* Wq = (const float*)d_in[1];
    const float* bq = (const float*)d_in[2];
    const float* Wk = (const float*)d_in[3];
    const float* bk = (const float*)d_in[4];
    const float* Wv = (const float*)d_in[5];
    const float* bv = (const float*)d_in[6];
    const float* Wo = (const float*)d_in[7];
    const float* bo = (const float*)d_in[8];
    float* out = (float*)d_out;

    char* ws = (char*)d_ws;
    const size_t MB16 = (size_t)16 * 1024 * 1024;
    unsigned short* qb = (unsigned short*)(ws);
    unsigned short* kb = (unsigned short*)(ws + MB16);
    unsigned short* vt = (unsigned short*)(ws + 2 * MB16);  // V^T [b][d][S]
    unsigned short* ab = (unsigned short*)(ws + 3 * MB16);

    dim3 gg(256, 2), bb(256);
    // scores in log2 domain: Q scale = d^-0.5 * log2(e)
    proj_gemm<false, 0><<<gg, bb, 0, stream>>>(x, Wq, bq, qb, 0.0625f * 1.44269504f);
    proj_gemm<false, 0><<<gg, bb, 0, stream>>>(x, Wk, bk, kb, 1.0f);
    proj_gemm<false, 2><<<gg, bb, 0, stream>>>(x, Wv, bv, vt, 1.0f);
    attn_kernel<<<dim3(128, NBATCH), bb, 0, stream>>>(qb, kb, vt, ab);
    proj_gemm<true, 1><<<gg, bb, 0, stream>>>(ab, Wo, bo, out, 1.0f);
}

// Round 12
// 428.277 us; speedup vs baseline: 1.7998x; 1.7998x over previous
//
#include <hip/hip_runtime.h>
#include <hip/hip_bf16.h>

typedef __attribute__((ext_vector_type(8))) short short8;
typedef __attribute__((ext_vector_type(4))) float f32x4;

#define SEQ 8192
#define NBATCH 4
#define NT (SEQ / 32)

static __device__ __forceinline__ unsigned short f2bf(float f) {
    __hip_bfloat16 h = __float2bfloat16(f);
    unsigned short u;
    __builtin_memcpy(&u, &h, 2);
    return u;
}

static __device__ __forceinline__ int4 pack8(float4 a, float4 b) {
    union { unsigned short s[8]; int4 i; } r;
    r.s[0] = f2bf(a.x); r.s[1] = f2bf(a.y); r.s[2] = f2bf(a.z); r.s[3] = f2bf(a.w);
    r.s[4] = f2bf(b.x); r.s[5] = f2bf(b.y); r.s[6] = f2bf(b.z); r.s[7] = f2bf(b.w);
    return r.i;
}

// C[M][N] = A[M][256] * W[N][256]^T (+bias)*scale.  Tile 128x128, 4 waves.
// OMODE: 0 = bf16 row-major, 1 = f32 row-major, 2 = bf16 transposed per batch
// (out[(b*256+col)*8192 + s], for V^T). (verified rounds 2-6)
template<bool A_BF16, int OMODE>
__global__ __launch_bounds__(256) void proj_gemm(
    const void* __restrict__ Ap, const float* __restrict__ W,
    const float* __restrict__ bias, void* __restrict__ Outp, float scale)
{
    __shared__ alignas(16) unsigned short As[128][40];
    __shared__ alignas(16) unsigned short Bs[128][40];

    const int tid  = threadIdx.x;
    const int lane = tid & 63;
    const int wv   = tid >> 6;
    const int wm   = (wv >> 1) * 64, wn = (wv & 1) * 64;
    const int lr   = lane & 15, lg = lane >> 4;
    const int m0   = blockIdx.x * 128;
    const int n0   = blockIdx.y * 128;

    const int srow = tid >> 1;
    const int skc  = (tid & 1) * 16;

    f32x4 acc[4][4] = {};

    for (int k0 = 0; k0 < 256; k0 += 32) {
        __syncthreads();
        if (A_BF16) {
            const unsigned short* a = (const unsigned short*)Ap + (size_t)(m0 + srow) * 256 + k0 + skc;
            int4 v0 = *(const int4*)a;
            int4 v1 = *(const int4*)(a + 8);
            *(int4*)&As[srow][skc]     = v0;
            *(int4*)&As[srow][skc + 8] = v1;
        } else {
            const float* a = (const float*)Ap + (size_t)(m0 + srow) * 256 + k0 + skc;
            const float4* a4 = (const float4*)a;
            *(int4*)&As[srow][skc]     = pack8(a4[0], a4[1]);
            *(int4*)&As[srow][skc + 8] = pack8(a4[2], a4[3]);
        }
        {
            const float* b = W + (size_t)(n0 + srow) * 256 + k0 + skc;
            const float4* b4 = (const float4*)b;
            *(int4*)&Bs[srow][skc]     = pack8(b4[0], b4[1]);
            *(int4*)&Bs[srow][skc + 8] = pack8(b4[2], b4[3]);
        }
        __syncthreads();

        short8 af[4], bfr[4];
        #pragma unroll
        for (int fm = 0; fm < 4; ++fm)
            af[fm] = *(const short8*)&As[wm + fm * 16 + lr][lg * 8];
        #pragma unroll
        for (int fn = 0; fn < 4; ++fn)
            bfr[fn] = *(const short8*)&Bs[wn + fn * 16 + lr][lg * 8];
        #pragma unroll
        for (int fm = 0; fm < 4; ++fm)
            #pragma unroll
            for (int fn = 0; fn < 4; ++fn)
                acc[fm][fn] = __builtin_amdgcn_mfma_f32_16x16x32_bf16(
                    af[fm], bfr[fn], acc[fm][fn], 0, 0, 0);
    }

    float bvals[4];
    #pragma unroll
    for (int fn = 0; fn < 4; ++fn) bvals[fn] = bias[n0 + wn + fn * 16 + lr];

    #pragma unroll
    for (int fm = 0; fm < 4; ++fm) {
        #pragma unroll
        for (int fn = 0; fn < 4; ++fn) {
            #pragma unroll
            for (int r = 0; r < 4; ++r) {
                const int row = m0 + wm + fm * 16 + lg * 4 + r;
                const int col = n0 + wn + fn * 16 + lr;
                float val = (acc[fm][fn][r] + bvals[fn]) * scale;
                if (OMODE == 1) {
                    ((float*)Outp)[(size_t)row * 256 + col] = val;
                } else if (OMODE == 0) {
                    ((unsigned short*)Outp)[(size_t)row * 256 + col] = f2bf(val);
                } else {  // V^T: [b][d=col][s]
                    const int bb = row >> 13, s = row & 8191;
                    ((unsigned short*)Outp)[((size_t)(bb * 256 + col) << 13) + s] = f2bf(val);
                }
            }
        }
    }
}

// Flash attention, round 12 = round 10 (best verified: 459us) + ones-column l:
// l is accumulated by MFMA — o_l[qt] = mfma(pa[qt], ones, o_l[qt]) makes every
// D column = sum_kv P, in the same lane mapping as o. Removes the rs row-sum
// (7 adds + 2 shfls serial chain), l_run bookkeeping, and the end-of-kernel
// Ls broadcast + barrier. o_l rescales with the same Cor as o.
// NO inline asm, NO setprio (r11 lesson: they pin the schedule and expose
// L2 latency). __launch_bounds__(256,2) guards the 2-blocks/CU occupancy.
// Verified r10 components: conflict-free 128B-interleaved K staging, swapped
// QK (D[kv][q]), per-lane log2 softmax, defer-rescale THR=11, Ps/Cor/Flg
// dbuf, PV lags 1 iter, V^T direct from global, one barrier/iter.
__global__ __launch_bounds__(256, 2) void attn_kernel(
    const unsigned short* __restrict__ Q, const unsigned short* __restrict__ K,
    const unsigned short* __restrict__ Vt, unsigned short* __restrict__ A)
{
    __shared__ alignas(16) unsigned short Ks[2][32][264];   // [buf][kv][d], pad +8
    __shared__ alignas(16) unsigned short Ps[2][4][16][40]; // [buf][qt][q][kv]
    __shared__ alignas(16) float Cor[2][4][16];
    __shared__ int Flg[2][4];

    const int tid  = threadIdx.x;
    const int lane = tid & 63;
    const int wv   = tid >> 6;
    const int lr   = lane & 15, lg = lane >> 4;
    const int b    = blockIdx.y;
    const size_t qblk = (size_t)b * SEQ + blockIdx.x * 64;

    // Q frags (B-operand): wave wv owns q-tile wv
    short8 aq[8];
    #pragma unroll
    for (int c = 0; c < 8; ++c)
        aq[c] = *(const short8*)&Q[(qblk + wv * 16 + lr) * 256 + c * 32 + lg * 8];

    float m_run = -1e30f;   // per-lane: q-row = lr (log2 domain)
    f32x4 o[4][4] = {};     // [qt][dt]: rows qt*16+lg*4+r, cols wv*64+dt*16+lr
    f32x4 o_l[4] = {};      // [qt]: l (sum of P) for rows qt*16+lg*4+r
    const short ONE = (short)0x3F80;   // bf16 1.0
    const short8 vone = {ONE, ONE, ONE, ONE, ONE, ONE, ONE, ONE};

    const int krow = tid >> 3;           // K staging: row 0..31
    const int kc8  = (tid & 7) * 8;      // chunk element offset (16B chunks)
    const unsigned short* Kb = K + (size_t)b * SEQ * 256;
    const unsigned short* Vb = Vt + ((size_t)b * 256 << 13);
    size_t vrow[4];
    #pragma unroll
    for (int dt = 0; dt < 4; ++dt)
        vrow[dt] = (size_t)(wv * 64 + dt * 16 + lr) << 13;

    // prologue: stage tile 0 into Ks[0] (128B-interleaved chunks)
    {
        const unsigned short* s = &Kb[(size_t)krow * 256 + kc8];
        int4 x0 = *(const int4*)(s);
        int4 x1 = *(const int4*)(s + 64);
        int4 x2 = *(const int4*)(s + 128);
        int4 x3 = *(const int4*)(s + 192);
        *(int4*)&Ks[0][krow][kc8]       = x0;
        *(int4*)&Ks[0][krow][kc8 + 64]  = x1;
        *(int4*)&Ks[0][krow][kc8 + 128] = x2;
        *(int4*)&Ks[0][krow][kc8 + 192] = x3;
    }
    __syncthreads();

    for (int t = 0; t < NT; ++t) {
        const int p = t & 1;
        const bool have = (t + 1 < NT);

        // issue K(t+1) loads early (latency hides under QK)
        int4 x0, x1, x2, x3;
        if (have) {
            const unsigned short* s = &Kb[((size_t)(t + 1) * 32 + krow) * 256 + kc8];
            x0 = *(const int4*)(s);
            x1 = *(const int4*)(s + 64);
            x2 = *(const int4*)(s + 128);
            x3 = *(const int4*)(s + 192);
        }
        // V^T frags for PV(t-1), direct from global (L2-resident)
        short8 vbr[4];
        if (t > 0) {
            const size_t kvp = (size_t)(t - 1) * 32 + lg * 8;
            #pragma unroll
            for (int dt = 0; dt < 4; ++dt)
                vbr[dt] = *(const short8*)&Vb[vrow[dt] + kvp];
        }

        // QK(t) from Ks[p] (swapped): s0 = kv 0..15, s1 = kv 16..31
        f32x4 s0 = {}, s1 = {};
        #pragma unroll
        for (int c = 0; c < 8; ++c) {
            short8 kb0 = *(const short8*)&Ks[p][lr][c * 32 + lg * 8];
            short8 kb1 = *(const short8*)&Ks[p][16 + lr][c * 32 + lg * 8];
            s0 = __builtin_amdgcn_mfma_f32_16x16x32_bf16(kb0, aq[c], s0, 0, 0, 0);
            s1 = __builtin_amdgcn_mfma_f32_16x16x32_bf16(kb1, aq[c], s1, 0, 0, 0);
        }

        // write staged K(t+1) into the other buffer (conflict-free map)
        if (have) {
            *(int4*)&Ks[p ^ 1][krow][kc8]       = x0;
            *(int4*)&Ks[p ^ 1][krow][kc8 + 64]  = x1;
            *(int4*)&Ks[p ^ 1][krow][kc8 + 128] = x2;
            *(int4*)&Ks[p ^ 1][krow][kc8 + 192] = x3;
        }

        // online softmax for q=lr (log2 domain), defer-rescale THR=11
        float mx = fmaxf(fmaxf(fmaxf(s0[0], s0[1]), fmaxf(s0[2], s0[3])),
                         fmaxf(fmaxf(s1[0], s1[1]), fmaxf(s1[2], s1[3])));
        mx = fmaxf(mx, __shfl_xor(mx, 16, 64));
        mx = fmaxf(mx, __shfl_xor(mx, 32, 64));

        const int need = __any(mx > m_run + 11.0f);
        if (need) {
            float mnew = fmaxf(m_run, mx);
            float corr = exp2f(m_run - mnew);
            m_run = mnew;
            if (lane < 16) Cor[p ^ 1][wv][lr] = corr;
        }
        if (lane == 0) Flg[p ^ 1][wv] = need;

        float p0[4], p1[4];
        #pragma unroll
        for (int r = 0; r < 4; ++r) {
            p0[r] = exp2f(s0[r] - m_run);
            p1[r] = exp2f(s1[r] - m_run);
        }

        {   // pack P -> Ps[p^1] (kv-contiguous per lane), 2x b64
            unsigned int w0 = (unsigned)f2bf(p0[0]) | ((unsigned)f2bf(p0[1]) << 16);
            unsigned int w1 = (unsigned)f2bf(p0[2]) | ((unsigned)f2bf(p0[3]) << 16);
            unsigned int w2 = (unsigned)f2bf(p1[0]) | ((unsigned)f2bf(p1[1]) << 16);
            unsigned int w3 = (unsigned)f2bf(p1[2]) | ((unsigned)f2bf(p1[3]) << 16);
            *(unsigned long long*)&Ps[p ^ 1][wv][lr][4 * lg] =
                (unsigned long long)w0 | ((unsigned long long)w1 << 32);
            *(unsigned long long*)&Ps[p ^ 1][wv][lr][16 + 4 * lg] =
                (unsigned long long)w2 | ((unsigned long long)w3 << 32);
        }

        // PV(t-1): P from Ps[p], rescale via Flg/Cor[p], V frags from global.
        // l accumulates via the ones-column MFMA (same Cor rescale as o).
        if (t > 0) {
            short8 pa[4];
            #pragma unroll
            for (int qt = 0; qt < 4; ++qt)
                pa[qt] = *(const short8*)&Ps[p][qt][lr][lg * 8];
            #pragma unroll
            for (int qt = 0; qt < 4; ++qt) {
                if (Flg[p][qt]) {
                    float4 c4 = *(const float4*)&Cor[p][qt][lg * 4];
                    #pragma unroll
                    for (int dt = 0; dt < 4; ++dt) {
                        o[qt][dt][0] *= c4.x; o[qt][dt][1] *= c4.y;
                        o[qt][dt][2] *= c4.z; o[qt][dt][3] *= c4.w;
                    }
                    o_l[qt][0] *= c4.x; o_l[qt][1] *= c4.y;
                    o_l[qt][2] *= c4.z; o_l[qt][3] *= c4.w;
                }
                #pragma unroll
                for (int dt = 0; dt < 4; ++dt)
                    o[qt][dt] = __builtin_amdgcn_mfma_f32_16x16x32_bf16(pa[qt], vbr[dt], o[qt][dt], 0, 0, 0);
                o_l[qt] = __builtin_amdgcn_mfma_f32_16x16x32_bf16(pa[qt], vone, o_l[qt], 0, 0, 0);
            }
        }
        __syncthreads();   // Ks[p^1] + Ps/Cor/Flg[p^1] visible; reads of [p] done
    }

    // epilogue: PV(NT-1) from Ps[NT&1]
    {
        const int p = NT & 1;
        const size_t kvp = (size_t)(NT - 1) * 32 + lg * 8;
        short8 vbr[4];
        #pragma unroll
        for (int dt = 0; dt < 4; ++dt)
            vbr[dt] = *(const short8*)&Vb[vrow[dt] + kvp];
        short8 pa[4];
        #pragma unroll
        for (int qt = 0; qt < 4; ++qt)
            pa[qt] = *(const short8*)&Ps[p][qt][lr][lg * 8];
        #pragma unroll
        for (int qt = 0; qt < 4; ++qt) {
            if (Flg[p][qt]) {
                float4 c4 = *(const float4*)&Cor[p][qt][lg * 4];
                #pragma unroll
                for (int dt = 0; dt < 4; ++dt) {
                    o[qt][dt][0] *= c4.x; o[qt][dt][1] *= c4.y;
                    o[qt][dt][2] *= c4.z; o[qt][dt][3] *= c4.w;
                }
                o_l[qt][0] *= c4.x; o_l[qt][1] *= c4.y;
                o_l[qt][2] *= c4.z; o_l[qt][3] *= c4.w;
            }
            #pragma unroll
            for (int dt = 0; dt < 4; ++dt)
                o[qt][dt] = __builtin_amdgcn_mfma_f32_16x16x32_bf16(pa[qt], vbr[dt], o[qt][dt], 0, 0, 0);
            o_l[qt] = __builtin_amdgcn_mfma_f32_16x16x32_bf16(pa[qt], vone, o_l[qt], 0, 0, 0);
        }
    }

    // normalize with the MFMA-accumulated l (already in o's lane mapping)
    #pragma unroll
    for (int qt = 0; qt < 4; ++qt) {
        float inv[4] = {1.f / o_l[qt][0], 1.f / o_l[qt][1],
                        1.f / o_l[qt][2], 1.f / o_l[qt][3]};
        #pragma unroll
        for (int dt = 0; dt < 4; ++dt)
            #pragma unroll
            for (int r = 0; r < 4; ++r)
                A[(qblk + qt * 16 + lg * 4 + r) * 256 + wv * 64 + dt * 16 + lr] =
                    f2bf(o[qt][dt][r] * inv[r]);
    }
}

extern "C" void kernel_launch(void* const* d_in, const int* in_sizes, int n_in,
                              void* d_out, int out_size, void* d_ws, size_t ws_size,
                              hipStream_t stream) {
    (void)in_sizes; (void)n_in; (void)out_size; (void)ws_size;
    const float* x  = (const float*)d_in[0];
    const float* Wq = (const float*)d_in[1];
    const float* bq = (const float*)d_in[2];
    const float* Wk = (const float*)d_in[3];
    const float* bk = (const float*)d_in[4];
    const float* Wv = (const float*)d_in[5];
    const float* bv = (const float*)d_in[6];
    const float* Wo = (const float*)d_in[7];
    const float* bo = (const float*)d_in[8];
    float* out = (float*)d_out;

    char* ws = (char*)d_ws;
    const size_t MB16 = (size_t)16 * 1024 * 1024;
    unsigned short* qb = (unsigned short*)(ws);
    unsigned short* kb = (unsigned short*)(ws + MB16);
    unsigned short* vt = (unsigned short*)(ws + 2 * MB16);  // V^T [b][d][S]
    unsigned short* ab = (unsigned short*)(ws + 3 * MB16);

    dim3 gg(256, 2), bb(256);
    // scores in log2 domain: Q scale = d^-0.5 * log2(e)
    proj_gemm<false, 0><<<gg, bb, 0, stream>>>(x, Wq, bq, qb, 0.0625f * 1.44269504f);
    proj_gemm<false, 0><<<gg, bb, 0, stream>>>(x, Wk, bk, kb, 1.0f);
    proj_gemm<false, 2><<<gg, bb, 0, stream>>>(x, Wv, bv, vt, 1.0f);
    attn_kernel<<<dim3(128, NBATCH), bb, 0, stream>>>(qb, kb, vt, ab);
    proj_gemm<true, 1><<<gg, bb, 0, stream>>>(ab, Wo, bo, out, 1.0f);
}